// Round 3
// baseline (210.748 us; speedup 1.0000x reference)
//
#include <hip/hip_runtime.h>

// Problem constants (reference: T=4096, N_ENVS=2048, fp32)
#define TT    4096
#define NENV  2048
#define N4    (NENV / 4)          // 512 float4 columns
#define L     8                   // timesteps per chunk
#define NCH   (TT / L)            // 512 chunks
#define NBLK  (NCH * 2)           // 1024 blocks (2 blocks x 256 thr per chunk)

#define GAMMA 0.99f
#define GL    (0.99f * 0.95f)

typedef float v4f __attribute__((ext_vector_type(4)));

// B = di + c*B ; A = c*A   (descending-i chunk affine, same fp order as R0)
#define STEP_AB(r_, v_, nv_, dn_, A_, B_)                    \
    {                                                        \
        const float nd = (dn_) ? 0.0f : 1.0f;                \
        const float di = (r_) + GAMMA * (nv_) * nd - (v_);   \
        const float c  = GL * nd;                            \
        (B_) = di + c * (B_);                                \
        (A_) = c * (A_);                                     \
    }

// g = di + c*g ; adv = g ; ret = g + v
#define STEP_OUT(r_, v_, nv_, dn_, g_, adv_, ret_)           \
    {                                                        \
        const float nd = (dn_) ? 0.0f : 1.0f;                \
        const float di = (r_) + GAMMA * (nv_) * nd - (v_);   \
        (g_) = di + GL * nd * (g_);                          \
        (adv_) = (g_);                                       \
        (ret_) = (g_) + (v_);                                \
    }

// ---- k2 helpers: 16-chunk groups, descending chunk index ----
#define P2_PREFETCH(abuf, bbuf, grp_)                        \
    _Pragma("unroll")                                        \
    for (int j = 0; j < 16; ++j) {                           \
        const int c = NCH - 1 - (grp_) * 16 - j;             \
        abuf[j] = As[c * NENV + col];                        \
        bbuf[j] = Bs[c * NENV + col];                        \
    }

#define P2_PROCESS(abuf, bbuf, grp_)                         \
    _Pragma("unroll")                                        \
    for (int j = 0; j < 16; ++j) {                           \
        const int c = NCH - 1 - (grp_) * 16 - j;             \
        Bs[c * NENV + col] = g;   /* g entering chunk c */   \
        g = fmaf(abuf[j], g, bbuf[j]);                       \
    }

// ---- k1: per-chunk affine (A,B).
//      All 32 float4 loads issued BEFORE sched_barrier(0): the scheduler may
//      not sink them past it, so ~32KB/wave stays in flight (vs ~6KB at
//      VGPR=52 in R2). (256,2) gives the 256-VGPR budget this needs.
__global__ __launch_bounds__(256, 2) void gae_k1(
    const float4* __restrict__ rp,  const float4* __restrict__ vp,
    const float4* __restrict__ np,  const int4*   __restrict__ dp,
    float4* __restrict__ wsA, float4* __restrict__ wsB)
{
    const int chunk = (int)blockIdx.x >> 1;
    const int c4    = (((int)blockIdx.x & 1) << 8) | (int)threadIdx.x;
    const int base  = chunk * (L * N4) + c4;

    float4 R[L], V[L], NV[L]; int4 DN[L];
#pragma unroll
    for (int i = L - 1; i >= 0; --i) {       // program order matches use order
        const int idx = base + i * N4;
        R[i]  = rp[idx];
        V[i]  = vp[idx];
        NV[i] = np[idx];
        DN[i] = dp[idx];
    }
    __builtin_amdgcn_sched_barrier(0);       // loads may not sink below here

    float Ax = 1.f, Ay = 1.f, Az = 1.f, Aw = 1.f;
    float Bx = 0.f, By = 0.f, Bz = 0.f, Bw = 0.f;
#pragma unroll
    for (int i = L - 1; i >= 0; --i) {
        STEP_AB(R[i].x, V[i].x, NV[i].x, DN[i].x, Ax, Bx);
        STEP_AB(R[i].y, V[i].y, NV[i].y, DN[i].y, Ay, By);
        STEP_AB(R[i].z, V[i].z, NV[i].z, DN[i].z, Az, Bz);
        STEP_AB(R[i].w, V[i].w, NV[i].w, DN[i].w, Aw, Bw);
    }
    wsA[chunk * N4 + c4] = make_float4(Ax, Ay, Az, Aw);
    wsB[chunk * N4 + c4] = make_float4(Bx, By, Bz, Bw);
}

// ---- k2: full-depth serial scan over 512 chunk affines (unchanged, proven).
__global__ __launch_bounds__(64) void gae_k2(
    const float* __restrict__ As, float* __restrict__ Bs)
{
    const int col = (int)blockIdx.x * 64 + (int)threadIdx.x;   // 32 blocks
    float a0[16], b0[16], a1[16], b1[16];
    float g = 0.0f;
    P2_PREFETCH(a0, b0, 0)
    for (int grp = 0; grp < NCH / 16; grp += 2) {
        P2_PREFETCH(a1, b1, grp + 1)
        P2_PROCESS(a0, b0, grp)
        if (grp + 2 < NCH / 16) { P2_PREFETCH(a0, b0, grp + 2) }
        P2_PROCESS(a1, b1, grp + 1)
    }
}

// ---- k3: replay with incoming g; deep preload + sched_barrier as in k1;
//      outputs stored NONTEMPORAL so 64 MiB of write-once data stops
//      evicting the inputs from L3 (k1's FETCH should drop 64 -> ~25 MiB).
__global__ __launch_bounds__(256, 2) void gae_k3(
    const float4* __restrict__ rp,  const float4* __restrict__ vp,
    const float4* __restrict__ np,  const int4*   __restrict__ dp,
    const float4* __restrict__ gin,
    float4* __restrict__ adv4, float4* __restrict__ ret4)
{
    const int chunk = (int)blockIdx.x >> 1;
    const int c4    = (((int)blockIdx.x & 1) << 8) | (int)threadIdx.x;
    const int base  = chunk * (L * N4) + c4;

    const float4 g0 = gin[chunk * N4 + c4];

    float4 R[L], V[L], NV[L]; int4 DN[L];
#pragma unroll
    for (int i = L - 1; i >= 0; --i) {
        const int idx = base + i * N4;
        R[i]  = rp[idx];
        V[i]  = vp[idx];
        NV[i] = np[idx];
        DN[i] = dp[idx];
    }
    __builtin_amdgcn_sched_barrier(0);

    float gx = g0.x, gy = g0.y, gz = g0.z, gw = g0.w;
#pragma unroll
    for (int i = L - 1; i >= 0; --i) {
        float4 a, t;
        STEP_OUT(R[i].x, V[i].x, NV[i].x, DN[i].x, gx, a.x, t.x);
        STEP_OUT(R[i].y, V[i].y, NV[i].y, DN[i].y, gy, a.y, t.y);
        STEP_OUT(R[i].z, V[i].z, NV[i].z, DN[i].z, gz, a.z, t.z);
        STEP_OUT(R[i].w, V[i].w, NV[i].w, DN[i].w, gw, a.w, t.w);
        const int idx = base + i * N4;
        v4f av; av.x = a.x; av.y = a.y; av.z = a.z; av.w = a.w;
        v4f tv; tv.x = t.x; tv.y = t.y; tv.z = t.z; tv.w = t.w;
        __builtin_nontemporal_store(av, (v4f*)&adv4[idx]);
        __builtin_nontemporal_store(tv, (v4f*)&ret4[idx]);
    }
}

extern "C" void kernel_launch(void* const* d_in, const int* in_sizes, int n_in,
                              void* d_out, int out_size, void* d_ws, size_t ws_size,
                              hipStream_t stream) {
    const float4* rp = (const float4*)d_in[0];
    const float4* vp = (const float4*)d_in[1];
    const float4* np = (const float4*)d_in[2];
    const int4*   dp = (const int4*)d_in[3];

    float4* adv4 = (float4*)d_out;
    float4* ret4 = adv4 + (size_t)TT * N4;

    float4* wsA = (float4*)d_ws;                 // 4 MiB (chunk A)
    float4* wsB = wsA + (size_t)NCH * N4;        // 4 MiB (chunk B -> incoming g)

    gae_k1<<<NBLK, 256, 0, stream>>>(rp, vp, np, dp, wsA, wsB);
    gae_k2<<<NENV / 64, 64, 0, stream>>>((const float*)wsA, (float*)wsB);
    gae_k3<<<NBLK, 256, 0, stream>>>(rp, vp, np, dp, wsB, adv4, ret4);
}

// Round 4
// 208.909 us; speedup vs baseline: 1.0088x; 1.0088x over previous
//
#include <hip/hip_runtime.h>

// Problem constants (reference: T=4096, N_ENVS=2048, fp32)
#define TT    4096
#define NENV  2048
#define N2    (NENV / 2)          // 1024 float2 columns
#define L     8                   // timesteps per chunk
#define NCH   (TT / L)            // 512 chunks
#define BPC   4                   // blocks per chunk (1024 f2cols / 256 thr)
#define NBLK  (NCH * BPC)         // 2048 blocks -> 8192 waves -> 32/CU (100%)

#define GAMMA 0.99f
#define GL    (0.99f * 0.95f)

typedef float v2f __attribute__((ext_vector_type(2)));

// B = di + c*B ; A = c*A   (descending-i chunk affine, same fp order as R0)
#define STEP_AB(r_, v_, nv_, dn_, A_, B_)                    \
    {                                                        \
        const float nd = (dn_) ? 0.0f : 1.0f;                \
        const float di = (r_) + GAMMA * (nv_) * nd - (v_);   \
        const float c  = GL * nd;                            \
        (B_) = di + c * (B_);                                \
        (A_) = c * (A_);                                     \
    }

// g = di + c*g ; adv = g ; ret = g + v
#define STEP_OUT(r_, v_, nv_, dn_, g_, adv_, ret_)           \
    {                                                        \
        const float nd = (dn_) ? 0.0f : 1.0f;                \
        const float di = (r_) + GAMMA * (nv_) * nd - (v_);   \
        (g_) = di + GL * nd * (g_);                          \
        (adv_) = (g_);                                       \
        (ret_) = (g_) + (v_);                                \
    }

// ---- k2 helpers: 16-chunk groups, descending chunk index ----
#define P2_PREFETCH(abuf, bbuf, grp_)                        \
    _Pragma("unroll")                                        \
    for (int j = 0; j < 16; ++j) {                           \
        const int c = NCH - 1 - (grp_) * 16 - j;             \
        abuf[j] = As[c * NENV + col];                        \
        bbuf[j] = Bs[c * NENV + col];                        \
    }

#define P2_PROCESS(abuf, bbuf, grp_)                         \
    _Pragma("unroll")                                        \
    for (int j = 0; j < 16; ++j) {                           \
        const int c = NCH - 1 - (grp_) * 16 - j;             \
        Bs[c * NENV + col] = g;   /* g entering chunk c */   \
        g = fmaf(abuf[j], g, bbuf[j]);                       \
    }

// ---- k1: per-chunk affine (A,B), float2 per thread.
//      2048 blocks x 256 thr = 32 waves/CU available (was 16). Rolling
//      load-consume loop, VGPR capped at 64 by (256,8) so full residency
//      is register-legal. TLP, not ILP, is the lever this round.
__global__ __launch_bounds__(256, 8) void gae_k1(
    const float2* __restrict__ rp,  const float2* __restrict__ vp,
    const float2* __restrict__ np,  const int2*   __restrict__ dp,
    float2* __restrict__ wsA, float2* __restrict__ wsB)
{
    const int chunk = (int)blockIdx.x >> 2;
    const int c2    = (((int)blockIdx.x & 3) << 8) | (int)threadIdx.x;
    const int base  = chunk * (L * N2) + c2;

    float Ax = 1.f, Ay = 1.f;
    float Bx = 0.f, By = 0.f;
#pragma unroll
    for (int i = L - 1; i >= 0; --i) {
        const int idx   = base + i * N2;
        const float2 r  = rp[idx];
        const float2 v  = vp[idx];
        const float2 nv = np[idx];
        const int2   dn = dp[idx];
        STEP_AB(r.x, v.x, nv.x, dn.x, Ax, Bx);
        STEP_AB(r.y, v.y, nv.y, dn.y, Ay, By);
    }
    wsA[chunk * N2 + c2] = make_float2(Ax, Ay);
    wsB[chunk * N2 + c2] = make_float2(Bx, By);
}

// ---- k2: full-depth serial scan over 512 chunk affines (unchanged, proven).
//      Layout is [NCH][NENV] scalar floats, identical to before.
__global__ __launch_bounds__(64) void gae_k2(
    const float* __restrict__ As, float* __restrict__ Bs)
{
    const int col = (int)blockIdx.x * 64 + (int)threadIdx.x;   // 32 blocks
    float a0[16], b0[16], a1[16], b1[16];
    float g = 0.0f;
    P2_PREFETCH(a0, b0, 0)
    for (int grp = 0; grp < NCH / 16; grp += 2) {
        P2_PREFETCH(a1, b1, grp + 1)
        P2_PROCESS(a0, b0, grp)
        if (grp + 2 < NCH / 16) { P2_PREFETCH(a0, b0, grp + 2) }
        P2_PROCESS(a1, b1, grp + 1)
    }
}

// ---- k3: replay with incoming g, float2 per thread, same geometry as k1.
//      Outputs nontemporal (write-once). Inputs cached (k1 re-reads next iter).
__global__ __launch_bounds__(256, 8) void gae_k3(
    const float2* __restrict__ rp,  const float2* __restrict__ vp,
    const float2* __restrict__ np,  const int2*   __restrict__ dp,
    const float2* __restrict__ gin,
    float2* __restrict__ adv2, float2* __restrict__ ret2)
{
    const int chunk = (int)blockIdx.x >> 2;
    const int c2    = (((int)blockIdx.x & 3) << 8) | (int)threadIdx.x;
    const int base  = chunk * (L * N2) + c2;

    const float2 g0 = gin[chunk * N2 + c2];
    float gx = g0.x, gy = g0.y;
#pragma unroll
    for (int i = L - 1; i >= 0; --i) {
        const int idx   = base + i * N2;
        const float2 r  = rp[idx];
        const float2 v  = vp[idx];
        const float2 nv = np[idx];
        const int2   dn = dp[idx];
        float ax, ay, tx, ty;
        STEP_OUT(r.x, v.x, nv.x, dn.x, gx, ax, tx);
        STEP_OUT(r.y, v.y, nv.y, dn.y, gy, ay, ty);
        v2f av; av.x = ax; av.y = ay;
        v2f tv; tv.x = tx; tv.y = ty;
        __builtin_nontemporal_store(av, (v2f*)&adv2[idx]);
        __builtin_nontemporal_store(tv, (v2f*)&ret2[idx]);
    }
}

extern "C" void kernel_launch(void* const* d_in, const int* in_sizes, int n_in,
                              void* d_out, int out_size, void* d_ws, size_t ws_size,
                              hipStream_t stream) {
    const float2* rp = (const float2*)d_in[0];
    const float2* vp = (const float2*)d_in[1];
    const float2* np = (const float2*)d_in[2];
    const int2*   dp = (const int2*)d_in[3];

    float2* adv2 = (float2*)d_out;
    float2* ret2 = adv2 + (size_t)TT * N2;

    float2* wsA = (float2*)d_ws;                 // 4 MiB (chunk A)
    float2* wsB = wsA + (size_t)NCH * N2;        // 4 MiB (chunk B -> incoming g)

    gae_k1<<<NBLK, 256, 0, stream>>>(rp, vp, np, dp, wsA, wsB);
    gae_k2<<<NENV / 64, 64, 0, stream>>>((const float*)wsA, (float*)wsB);
    gae_k3<<<NBLK, 256, 0, stream>>>(rp, vp, np, dp, wsB, adv2, ret2);
}